// Round 1
// 259.410 us; speedup vs baseline: 1.2056x; 1.2056x over previous
//
#include <hip/hip_runtime.h>

// Bilinear warp (grid_sample, zeros padding) of frame_t (8,64,256,256) fp32
// by flow_field (8,2,256,256) fp32.
//   ix = px + 0.5*flow_x ; iy = py + 0.5*flow_y   (normalization collapses)
//
// R4 structure — R3 was latency-bound at 2 blocks/CU (64 KiB LDS window,
// OccupancyPercent 21.7, VALUBusy 40%):
//  - Halo cut 24 -> 12 rows (3 sigma of disp~N(0,4)): window 40 rows =
//    40 KiB -> 4 blocks/CU (160 KiB LDS exactly) = 16 waves/CU.
//  - All 16 rows of flow (fx,fy) prefetched into registers up front:
//    32 coalesced loads issued back-to-back, one vmcnt wait instead of 16
//    serialized per-row latency exposures.
//  - Fast path: single wave-uniform __all() "all 4 taps in window" branch
//    (taken ~84% of wave-rows); slow path keeps per-tap LDS/global select.
//  - Validity folded into weights (cndmask), 6-FMA 2-level blend tree.
//  - blockIdx: low 3 bits = b -> XCD-local image; band-fastest within
//    channel -> consecutive windows overlap 28/40 rows in L2.
//  - non-temporal output stores (streaming, don't pollute L2).

#define B_ 8
#define C_ 64
#define H_ 256
#define W_ 256
#define HW_ (H_ * W_)
#define BAND 16
#define NBAND (H_ / BAND)
#define HALO 12
#define WROWS (BAND + 2 * HALO)        // 40 rows
#define WFLOATS (WROWS * W_)           // 10240 floats = 40 KiB

__global__ __launch_bounds__(256, 4) void warp_bilinear_kernel(
    const float* __restrict__ frame,   // (8,64,256,256)
    const float* __restrict__ flow,    // (8,2,256,256)
    float* __restrict__ out)           // (8,64,256,256)
{
    __shared__ float win[WFLOATS];

    const int blk  = blockIdx.x;
    const int b    = blk & 7;          // XCD-local batch
    const int t    = blk >> 3;
    const int band = t & (NBAND - 1);  // fastest: consecutive windows overlap
    const int c    = t >> 4;

    const int r0  = band * BAND;
    const int wlo = r0 - HALO;         // first window row (may be <0)

    const int tid = threadIdx.x;       // 0..255
    const float* __restrict__ src = frame + ((size_t)(b * C_ + c)) * HW_;

    // ---- stage 40 rows x 256 cols into LDS, coalesced float4 ----
#pragma unroll
    for (int it = 0; it < WFLOATS / (256 * 4); ++it) {   // 10 iters
        const int lin = it * 1024 + tid * 4;             // float index in window
        const int wr  = lin >> 8;                        // window row
        const int wx  = lin & 255;
        const int gy  = min(max(wlo + wr, 0), H_ - 1);   // clamp (dups are L2 hits)
        const float4 v = *(const float4*)(src + gy * W_ + wx);
        *(float4*)(win + lin) = v;
    }
    __syncthreads();

    // ---- prefetch all flow for this band into registers ----
    const int px = tid;
    const int spbase = r0 * W_ + px;
    const float* __restrict__ flx = flow + (size_t)(b * 2 + 0) * HW_;
    const float* __restrict__ fly = flow + (size_t)(b * 2 + 1) * HW_;

    float fx[BAND], fy[BAND];
#pragma unroll
    for (int r = 0; r < BAND; ++r) {
        fx[r] = flx[spbase + r * W_];
        fy[r] = fly[spbase + r * W_];
    }

    float* __restrict__ dst = out + ((size_t)(b * C_ + c)) * HW_;

    // ---- gather 16 band rows ----
#pragma unroll
    for (int r = 0; r < BAND; ++r) {
        const int py = r0 + r;
        const int sp = spbase + r * W_;

        const float ix = (float)px + 0.5f * fx[r];
        const float iy = (float)py + 0.5f * fy[r];

        const float ix0f = floorf(ix);
        const float iy0f = floorf(iy);
        const float wx1 = ix - ix0f;
        const float wx0 = 1.0f - wx1;
        const float wy1 = iy - iy0f;
        const float wy0 = 1.0f - wy1;

        const int ix0 = (int)ix0f;
        const int iy0 = (int)iy0f;
        const int ix1 = ix0 + 1;
        const int iy1 = iy0 + 1;

        // validity folded into weights (v_cmp + cndmask each)
        const float wx0v = ((unsigned)ix0 < (unsigned)W_) ? wx0 : 0.0f;
        const float wx1v = ((unsigned)ix1 < (unsigned)W_) ? wx1 : 0.0f;
        const float wy0v = ((unsigned)iy0 < (unsigned)H_) ? wy0 : 0.0f;
        const float wy1v = ((unsigned)iy1 < (unsigned)H_) ? wy1 : 0.0f;

        const int xc0 = min(max(ix0, 0), W_ - 1);
        const int xc1 = min(max(ix1, 0), W_ - 1);
        const int yc0 = min(max(iy0, 0), H_ - 1);
        const int yc1 = min(max(iy1, 0), H_ - 1);

        const int wr0 = yc0 - wlo;
        const int wr1 = yc1 - wlo;
        const bool in0 = (unsigned)wr0 < (unsigned)WROWS;
        const bool in1 = (unsigned)wr1 < (unsigned)WROWS;

        float t00, t01, t10, t11;
        if (__builtin_expect(__all(in0 && in1), 1)) {
            // fast path: all 4 taps in the LDS window (wave-uniform)
            t00 = win[wr0 * W_ + xc0];
            t01 = win[wr0 * W_ + xc1];
            t10 = win[wr1 * W_ + xc0];
            t11 = win[wr1 * W_ + xc1];
        } else {
            // rare: some lane's tap fell outside the staged window
            t00 = in0 ? win[wr0 * W_ + xc0] : src[yc0 * W_ + xc0];
            t01 = in0 ? win[wr0 * W_ + xc1] : src[yc0 * W_ + xc1];
            t10 = in1 ? win[wr1 * W_ + xc0] : src[yc1 * W_ + xc0];
            t11 = in1 ? win[wr1 * W_ + xc1] : src[yc1 * W_ + xc1];
        }

        const float h0 = wx0v * t00 + wx1v * t01;   // row iy0
        const float h1 = wx0v * t10 + wx1v * t11;   // row iy1
        const float v  = wy0v * h0 + wy1v * h1;

        __builtin_nontemporal_store(v, dst + sp);
    }
}

extern "C" void kernel_launch(void* const* d_in, const int* in_sizes, int n_in,
                              void* d_out, int out_size, void* d_ws, size_t ws_size,
                              hipStream_t stream) {
    const float* frame = (const float*)d_in[0];
    const float* flow  = (const float*)d_in[1];
    float* out = (float*)d_out;

    dim3 grid(B_ * C_ * NBAND);   // 8192 blocks: (c, band, b) with b fastest
    dim3 block(256);
    warp_bilinear_kernel<<<grid, block, 0, stream>>>(frame, flow, out);
}

// Round 2
// 247.128 us; speedup vs baseline: 1.2655x; 1.0497x over previous
//
#include <hip/hip_runtime.h>

// Bilinear warp (grid_sample, zeros padding) of frame_t (8,64,256,256) fp32
// by flow_field (8,2,256,256) fp32.
//   ix = px + 0.5*flow_x ; iy = py + 0.5*flow_y   (normalization collapses)
//
// R5 structure — R4 was latency-bound with all pipes ~35-40% (VALU 41%,
// LDS ~34%, VMEM ~28%, occupancy capped at 4 blocks/CU by 40KB LDS):
//  - BRANCHLESS main loop: always read a 2x2 LDS stencil at
//    (clamped row, clamped col) -> straight-line 16-row unroll the compiler
//    can software-pipeline (no per-row __all branch breaking scheduling).
//  - Image-border clamp semantics reproduced exactly by 8 cndmask edge
//    selects (x: ix0>=255 / ix0<0, y: iy0>=255 / iy0<0) instead of 4
//    per-tap clamp+address chains -> 1 address chain, LDS reads pair into
//    ds_read2/read2st64 (col +4B, row +1024B off one base).
//  - Window misses (|disp_y|>~11.5, ~0.3%/px) recorded in a 16-bit badmask;
//    fixed up AFTER the loop with global taps (execz-skipped per row) ->
//    rare global latency no longer serializes the hot loop.
//  - Flow prefetch issued before __syncthreads: latency hides under the
//    staging drain.
//  - 40 KiB window (band 16 + halo 12) = 4 blocks/CU = 16 waves/CU.
//  - blockIdx: low 3 bits = b -> XCD-local image; band-fastest -> 28/40-row
//    L2 overlap between consecutive windows.

#define B_ 8
#define C_ 64
#define H_ 256
#define W_ 256
#define HW_ (H_ * W_)
#define BAND 16
#define NBAND (H_ / BAND)
#define HALO 12
#define WROWS (BAND + 2 * HALO)        // 40 rows
#define WFLOATS (WROWS * W_)           // 10240 floats = 40 KiB
#define WMAXBR (WROWS - 2)             // 38: max base row (reads brw, brw+1)

__global__ __launch_bounds__(256, 4) void warp_bilinear_kernel(
    const float* __restrict__ frame,   // (8,64,256,256)
    const float* __restrict__ flow,    // (8,2,256,256)
    float* __restrict__ out)           // (8,64,256,256)
{
    __shared__ float win[WFLOATS];

    const int blk  = blockIdx.x;
    const int b    = blk & 7;          // XCD-local batch
    const int t    = blk >> 3;
    const int band = t & (NBAND - 1);
    const int c    = t >> 4;

    const int r0  = band * BAND;
    const int wlo = r0 - HALO;         // first window row (may be <0)

    const int tid = threadIdx.x;       // 0..255
    const float* __restrict__ src = frame + ((size_t)(b * C_ + c)) * HW_;

    // ---- stage 40 rows x 256 cols into LDS, coalesced float4 ----
#pragma unroll
    for (int it = 0; it < WFLOATS / (256 * 4); ++it) {   // 10 iters
        const int lin = it * 1024 + tid * 4;
        const int wr  = lin >> 8;
        const int wx  = lin & 255;
        const int gy  = min(max(wlo + wr, 0), H_ - 1);   // clamp (dups L2-hit)
        const float4 v = *(const float4*)(src + gy * W_ + wx);
        *(float4*)(win + lin) = v;
    }

    // ---- prefetch flow for this band (latency hides under staging drain) --
    const int px = tid;
    const int spbase = r0 * W_ + px;
    const float* __restrict__ flx = flow + (size_t)(b * 2 + 0) * HW_;
    const float* __restrict__ fly = flow + (size_t)(b * 2 + 1) * HW_;

    float fx[BAND], fy[BAND];
#pragma unroll
    for (int r = 0; r < BAND; ++r) {
        fx[r] = flx[spbase + r * W_];
        fy[r] = fly[spbase + r * W_];
    }

    __syncthreads();

    float* __restrict__ dst = out + ((size_t)(b * C_ + c)) * HW_;

    unsigned badmask = 0u;

    // ---- branchless gather: 16 rows, straight-line ----
#pragma unroll
    for (int r = 0; r < BAND; ++r) {
        const int py = r0 + r;

        const float ix = (float)px + 0.5f * fx[r];
        const float iy = (float)py + 0.5f * fy[r];

        const float ix0f = floorf(ix);
        const float iy0f = floorf(iy);
        const float wx1 = ix - ix0f;
        const float wx0 = 1.0f - wx1;
        const float wy1 = iy - iy0f;
        const float wy0 = 1.0f - wy1;

        const int ix0 = (int)ix0f;
        const int iy0 = (int)iy0f;

        // validity folded into weights (zeros padding)
        const float wx0v = ((unsigned)ix0       < (unsigned)W_) ? wx0 : 0.0f;
        const float wx1v = ((unsigned)(ix0 + 1) < (unsigned)W_) ? wx1 : 0.0f;
        const float wy0v = ((unsigned)iy0       < (unsigned)H_) ? wy0 : 0.0f;
        const float wy1v = ((unsigned)(iy0 + 1) < (unsigned)H_) ? wy1 : 0.0f;

        // clamped 2x2 stencil base (always safely inside the window)
        const int base = min(max(ix0, 0), W_ - 2);   // 0..254
        const int bry  = min(max(iy0, 0), H_ - 2);   // 0..254
        const int brw  = bry - wlo;
        const int brwc = min(max(brw, 0), WMAXBR);   // 0..38

        badmask |= ((unsigned)brw > (unsigned)WMAXBR) ? (1u << r) : 0u;

        const int o0 = brwc * W_ + base;
        const float a  = win[o0];            // (row lo, col lo)
        const float bb = win[o0 + 1];        // (row lo, col hi)
        const float cl = win[o0 + W_];       // (row hi, col lo)
        const float dl = win[o0 + W_ + 1];   // (row hi, col hi)

        // exact clamp semantics via edge selects
        const bool xhi = (ix0 >= W_ - 1);    // xc0 = 255 = base+1
        const bool xlo = (ix0 < 0);          // xc1 = 0   = base
        const float rl0 = xhi ? bb : a;      // row lo, x0 tap
        const float rh0 = xhi ? dl : cl;     // row hi, x0 tap
        const float rl1 = xlo ? a  : bb;     // row lo, x1 tap
        const float rh1 = xlo ? cl : dl;     // row hi, x1 tap

        const bool yhi = (iy0 >= H_ - 1);    // yc0 = 255 = row hi
        const bool ylo = (iy0 < 0);          // yc1 = 0   = row lo
        const float t00 = yhi ? rh0 : rl0;
        const float t10 = ylo ? rl0 : rh0;
        const float t01 = yhi ? rh1 : rl1;
        const float t11 = ylo ? rl1 : rh1;

        const float h0 = wx0v * t00 + wx1v * t01;
        const float h1 = wx0v * t10 + wx1v * t11;
        const float v  = wy0v * h0 + wy1v * h1;

        __builtin_nontemporal_store(v, dst + spbase + r * W_);
    }

    // ---- rare fix-up: lanes whose 2x2 stencil fell outside the window ----
    if (__any(badmask != 0u)) {
#pragma unroll 1
        for (int r = 0; r < BAND; ++r) {
            if ((badmask >> r) & 1u) {
                const int py = r0 + r;

                const float ix = (float)px + 0.5f * fx[r];
                const float iy = (float)py + 0.5f * fy[r];

                const float ix0f = floorf(ix);
                const float iy0f = floorf(iy);
                const float wx1 = ix - ix0f;
                const float wx0 = 1.0f - wx1;
                const float wy1 = iy - iy0f;
                const float wy0 = 1.0f - wy1;

                const int ix0 = (int)ix0f;
                const int iy0 = (int)iy0f;

                const float wx0v = ((unsigned)ix0       < (unsigned)W_) ? wx0 : 0.0f;
                const float wx1v = ((unsigned)(ix0 + 1) < (unsigned)W_) ? wx1 : 0.0f;
                const float wy0v = ((unsigned)iy0       < (unsigned)H_) ? wy0 : 0.0f;
                const float wy1v = ((unsigned)(iy0 + 1) < (unsigned)H_) ? wy1 : 0.0f;

                const int xc0 = min(max(ix0, 0), W_ - 1);
                const int xc1 = min(max(ix0 + 1, 0), W_ - 1);
                const int yc0 = min(max(iy0, 0), H_ - 1);
                const int yc1 = min(max(iy0 + 1, 0), H_ - 1);

                const float t00 = src[yc0 * W_ + xc0];
                const float t01 = src[yc0 * W_ + xc1];
                const float t10 = src[yc1 * W_ + xc0];
                const float t11 = src[yc1 * W_ + xc1];

                const float h0 = wx0v * t00 + wx1v * t01;
                const float h1 = wx0v * t10 + wx1v * t11;
                const float v  = wy0v * h0 + wy1v * h1;

                __builtin_nontemporal_store(v, dst + spbase + r * W_);
            }
        }
    }
}

extern "C" void kernel_launch(void* const* d_in, const int* in_sizes, int n_in,
                              void* d_out, int out_size, void* d_ws, size_t ws_size,
                              hipStream_t stream) {
    const float* frame = (const float*)d_in[0];
    const float* flow  = (const float*)d_in[1];
    float* out = (float*)d_out;

    dim3 grid(B_ * C_ * NBAND);   // 8192 blocks: (c, band, b) with b fastest
    dim3 block(256);
    warp_bilinear_kernel<<<grid, block, 0, stream>>>(frame, flow, out);
}